// Round 5
// baseline (244.750 us; speedup 1.0000x reference)
//
#include <hip/hip_runtime.h>
#include <hip/hip_bf16.h>
#include <math.h>

#define VOCAB 50257
#define EMB   1024
#define HID   1024
#define BATCH 64
#define SEQ   512
#define LOGITS_LD 50304
#define SCH   16                  // s-rows per attention chunk
#define NCHUNK (SEQ / SCH)        // 32

typedef __attribute__((ext_vector_type(8))) short bf16x8;
typedef __attribute__((ext_vector_type(4))) float f32x4;

__device__ inline short f2bf(float x) {
    __hip_bfloat16 h = __float2bfloat16(x);
    return *reinterpret_cast<short*>(&h);
}

__device__ inline bf16x8 cvt8(const float4& a, const float4& b) {
    bf16x8 r;
    r[0] = f2bf(a.x); r[1] = f2bf(a.y); r[2] = f2bf(a.z); r[3] = f2bf(a.w);
    r[4] = f2bf(b.x); r[5] = f2bf(b.y); r[6] = f2bf(b.z); r[7] = f2bf(b.w);
    return r;
}

// ---------------------------------------------------------------------------
// Unified direct-stream MFMA GEMM, up to 3 problems (blockIdx.y), split-K
// (blockIdx.z), fp32 A with optional row-gather, fp32 W converted in-flight.
// 128 threads = 2 waves; wave computes 16 cols x 64 rows. Tile = 32 cols.
// C_part[kz][64][ldc] = A[64][Kslice] @ W[N][Kslice]^T (+bias if ADD_BIAS)
// ---------------------------------------------------------------------------
struct Prob {
    const float* A;      // [64][K] fp32
    const int*   gidx;   // optional row gather (embedding), else null
    const float* W;      // [N][K] fp32
    const float* bias;   // [N] (only if ADD_BIAS)
    float*       C;      // [nsplit][64][ldc]
    int N, K, ldc;
};

template <int KSLEN, int ADD_BIAS>
__global__ __launch_bounds__(128) void gemm_k(Prob p0, Prob p1, Prob p2)
{
    Prob P = (blockIdx.y == 0) ? p0 : ((blockIdx.y == 1) ? p1 : p2);

    const int lane = threadIdx.x & 63;
    const int wv   = threadIdx.x >> 6;     // 0..1
    const int rowi = lane & 15;
    const int kgi  = lane >> 4;            // 0..3
    const int col  = blockIdx.x * 32 + wv * 16 + rowi;
    const int wcol = min(col, P.N - 1);
    const int kbase = blockIdx.z * KSLEN + kgi * 8;

    const float* wp = P.W + (size_t)wcol * P.K + kbase;
    const float* ap[4];
#pragma unroll
    for (int mt = 0; mt < 4; ++mt) {
        int r  = rowi + mt * 16;
        int ar = P.gidx ? P.gidx[r] : r;
        ap[mt] = P.A + (size_t)ar * P.K + kbase;
    }

    f32x4 acc[4] = {};

    float4 wa = *(const float4*)wp;
    float4 wb = *(const float4*)(wp + 4);
    float4 aa[4], ab[4];
#pragma unroll
    for (int mt = 0; mt < 4; ++mt) {
        aa[mt] = *(const float4*)ap[mt];
        ab[mt] = *(const float4*)(ap[mt] + 4);
    }

#pragma unroll
    for (int ks = 32; ks <= KSLEN; ks += 32) {
        float4 nwa = {}, nwb = {}, naa[4] = {}, nab[4] = {};
        if (ks < KSLEN) {
            nwa = *(const float4*)(wp + ks);
            nwb = *(const float4*)(wp + ks + 4);
#pragma unroll
            for (int mt = 0; mt < 4; ++mt) {
                naa[mt] = *(const float4*)(ap[mt] + ks);
                nab[mt] = *(const float4*)(ap[mt] + ks + 4);
            }
        }
        bf16x8 b = cvt8(wa, wb);
#pragma unroll
        for (int mt = 0; mt < 4; ++mt) {
            bf16x8 a = cvt8(aa[mt], ab[mt]);
            acc[mt] = __builtin_amdgcn_mfma_f32_16x16x32_bf16(a, b, acc[mt], 0, 0, 0);
        }
        wa = nwa; wb = nwb;
#pragma unroll
        for (int mt = 0; mt < 4; ++mt) { aa[mt] = naa[mt]; ab[mt] = nab[mt]; }
    }

    if (col < P.N) {
        float bv = ADD_BIAS ? P.bias[col] : 0.0f;
        float* C = P.C + (size_t)blockIdx.z * 64 * P.ldc;
#pragma unroll
        for (int mt = 0; mt < 4; ++mt)
#pragma unroll
            for (int r = 0; r < 4; ++r) {
                int row = mt * 16 + kgi * 4 + r;
                C[(size_t)row * P.ldc + col] = acc[mt][r] + bv;
            }
    }
}

// ---------------------------------------------------------------------------
// GRU gate fusion over split-K partials (NZI for gi, NZH for gh).
// ---------------------------------------------------------------------------
template <int NZI, int NZH>
__global__ __launch_bounds__(256) void gru_gate_k(
    const float* __restrict__ pgi, const float* __restrict__ pgh,
    const float* __restrict__ b_ih, const float* __restrict__ b_hh,
    const float* __restrict__ hprev, float* __restrict__ out_hidden,
    float* __restrict__ h_out, float* __restrict__ ci)
{
    int i = blockIdx.x * 256 + threadIdx.x;   // 0 .. 65536
    int b = i >> 10, j = i & 1023;
    size_t base = (size_t)b * 3072 + j;
    float ir = b_ih[j], iz = b_ih[j + 1024], in_ = b_ih[j + 2048];
    float hr = b_hh[j], hz = b_hh[j + 1024], hn  = b_hh[j + 2048];
#pragma unroll
    for (int z = 0; z < NZI; ++z) {
        size_t o = (size_t)z * 64 * 3072 + base;
        ir += pgi[o]; iz += pgi[o + 1024]; in_ += pgi[o + 2048];
    }
#pragma unroll
    for (int z = 0; z < NZH; ++z) {
        size_t o = (size_t)z * 64 * 3072 + base;
        hr += pgh[o]; hz += pgh[o + 1024]; hn  += pgh[o + 2048];
    }
    float r = 1.0f / (1.0f + expf(-(ir + hr)));
    float z = 1.0f / (1.0f + expf(-(iz + hz)));
    float n = tanhf(in_ + r * hn);
    float v = (1.0f - z) * n + z * hprev[i];
    out_hidden[i] = v;
    if (h_out) h_out[i] = v;
    if (ci)    ci[(size_t)b * 2048 + j] = v;
}

// ---------------------------------------------------------------------------
// Single-pass flash attention chunk: per (chunk of 16 s, b).
// ---------------------------------------------------------------------------
__global__ __launch_bounds__(256) void attn_fused_k(
    const float* __restrict__ h1, const float* __restrict__ enc,
    float* __restrict__ pctx, float* __restrict__ pm, float* __restrict__ ps)
{
    const int b = blockIdx.y, ck = blockIdx.x;
    __shared__ float hs[HID];
    __shared__ float es[SCH][HID];
    __shared__ float sc[SCH];
    const int tid = threadIdx.x, wv = tid >> 6, lane = tid & 63;

    ((float4*)hs)[tid] = ((const float4*)(h1 + (size_t)b * HID))[tid];
    const float* ebase = enc + ((size_t)(ck * SCH) * BATCH + b) * HID;
#pragma unroll
    for (int i = 0; i < SCH; ++i) {
        int idx = tid + i * 256;
        int r = idx >> 8, c = idx & 255;
        ((float4*)es[r])[c] = ((const float4*)(ebase + (size_t)r * BATCH * HID))[c];
    }
    __syncthreads();

#pragma unroll
    for (int i = 0; i < 4; ++i) {
        int r = wv * 4 + i;
        float acc = 0.0f;
#pragma unroll
        for (int seg = 0; seg < 4; ++seg) {
            float4 ev = ((const float4*)es[r])[lane + seg * 64];
            float4 hv = ((const float4*)hs)[lane + seg * 64];
            acc += ev.x * hv.x + ev.y * hv.y + ev.z * hv.z + ev.w * hv.w;
        }
        for (int off = 32; off; off >>= 1) acc += __shfl_down(acc, off);
        if (lane == 0) sc[r] = acc;
    }
    __syncthreads();

    float m = sc[0];
#pragma unroll
    for (int s = 1; s < SCH; ++s) m = fmaxf(m, sc[s]);
    float p[SCH];
    float sum = 0.0f;
#pragma unroll
    for (int s = 0; s < SCH; ++s) { p[s] = expf(sc[s] - m); sum += p[s]; }

    float4 cacc = {0.0f, 0.0f, 0.0f, 0.0f};
#pragma unroll
    for (int s = 0; s < SCH; ++s) {
        float4 ev = ((const float4*)es[s])[tid];
        cacc.x += p[s] * ev.x; cacc.y += p[s] * ev.y;
        cacc.z += p[s] * ev.z; cacc.w += p[s] * ev.w;
    }
    ((float4*)(pctx + ((size_t)ck * BATCH + b) * HID))[tid] = cacc;
    if (tid == 0) { pm[b * NCHUNK + ck] = m; ps[b * NCHUNK + ck] = sum; }
}

// ---------------------------------------------------------------------------
// Attention combine: merge 32 chunk partials -> ci[:,1024:] (fp32)
// ---------------------------------------------------------------------------
__global__ __launch_bounds__(256) void attn_comb_k(
    const float* __restrict__ pctx, const float* __restrict__ pm,
    const float* __restrict__ ps, float* __restrict__ ci)
{
    const int b = blockIdx.x, tid = threadIdx.x;
    float m = -INFINITY;
#pragma unroll
    for (int c = 0; c < NCHUNK; ++c) m = fmaxf(m, pm[b * NCHUNK + c]);
    float w[NCHUNK]; float tot = 0.0f;
#pragma unroll
    for (int c = 0; c < NCHUNK; ++c) {
        w[c] = expf(pm[b * NCHUNK + c] - m);
        tot += ps[b * NCHUNK + c] * w[c];
    }
    float inv = 1.0f / tot;
    float4 acc = {0.0f, 0.0f, 0.0f, 0.0f};
#pragma unroll
    for (int c = 0; c < NCHUNK; ++c) {
        float4 v = ((const float4*)(pctx + ((size_t)c * BATCH + b) * HID))[tid];
        acc.x += w[c] * v.x; acc.y += w[c] * v.y;
        acc.z += w[c] * v.z; acc.w += w[c] * v.w;
    }
    float4 o = {acc.x * inv, acc.y * inv, acc.z * inv, acc.w * inv};
    ((float4*)(ci + (size_t)b * 2048 + 1024))[tid] = o;
}

// ---------------------------------------------------------------------------
// Concat combine: co = tanh(sum of 8 partials + bias)  (fp32)
// ---------------------------------------------------------------------------
__global__ __launch_bounds__(256) void concat_comb_k(
    const float* __restrict__ pco, const float* __restrict__ bias,
    float* __restrict__ co)
{
    int i = blockIdx.x * 256 + threadIdx.x;
    int j = i & 1023;
    float v = bias[j];
#pragma unroll
    for (int z = 0; z < 8; ++z) v += pco[(size_t)z * 65536 + i];
    co[i] = tanhf(v);
}

// ---------------------------------------------------------------------------
// Partial logit stats per (b, 1/8 of VOCAB)
// ---------------------------------------------------------------------------
#define VCHUNK 6284
__global__ __launch_bounds__(256) void stats_part_k(
    const float* __restrict__ logits, float* __restrict__ vmax,
    float* __restrict__ vsum, int ldc)
{
    int b = blockIdx.y, ch = blockIdx.x;
    int v0 = ch * VCHUNK;
    int v1 = min(v0 + VCHUNK, VOCAB);
    const float* row = logits + (size_t)b * ldc;
    float m = -INFINITY;
    for (int v = v0 + threadIdx.x; v < v1; v += 256) m = fmaxf(m, row[v]);
    __shared__ float red[4];
    for (int off = 32; off; off >>= 1) m = fmaxf(m, __shfl_xor(m, off));
    int wave = threadIdx.x >> 6, lane = threadIdx.x & 63;
    if (lane == 0) red[wave] = m;
    __syncthreads();
    m = fmaxf(fmaxf(red[0], red[1]), fmaxf(red[2], red[3]));
    float ssum = 0.0f;
    for (int v = v0 + threadIdx.x; v < v1; v += 256) ssum += expf(row[v] - m);
    for (int off = 32; off; off >>= 1) ssum += __shfl_xor(ssum, off);
    __syncthreads();
    if (lane == 0) red[wave] = ssum;
    __syncthreads();
    if (threadIdx.x == 0) {
        vmax[b * 8 + ch] = m;
        vsum[b * 8 + ch] = red[0] + red[1] + red[2] + red[3];
    }
}

// ---------------------------------------------------------------------------
// Softmax normalize over VOCAB
// ---------------------------------------------------------------------------
__global__ __launch_bounds__(256) void softmax_v_k(
    const float* __restrict__ logits, const float* __restrict__ vmax,
    const float* __restrict__ vsum, float* __restrict__ out, int ldc)
{
    int b = blockIdx.y;
    float m = -INFINITY;
#pragma unroll
    for (int i = 0; i < 8; ++i) m = fmaxf(m, vmax[b * 8 + i]);
    float tot = 0.0f;
#pragma unroll
    for (int i = 0; i < 8; ++i) tot += vsum[b * 8 + i] * expf(vmax[b * 8 + i] - m);
    float inv = 1.0f / tot;
    int v = blockIdx.x * 1024 + threadIdx.x * 4;
    if (v + 3 < VOCAB) {
        float4 lv = *reinterpret_cast<const float4*>(logits + (size_t)b * ldc + v);
        float4 o;
        o.x = expf(lv.x - m) * inv; o.y = expf(lv.y - m) * inv;
        o.z = expf(lv.z - m) * inv; o.w = expf(lv.w - m) * inv;
        *reinterpret_cast<float4*>(out + (size_t)b * VOCAB + v) = o;
    } else {
        for (int k = 0; k < 4 && v + k < VOCAB; ++k)
            out[(size_t)b * VOCAB + v + k] = expf(logits[(size_t)b * ldc + v + k] - m) * inv;
    }
}

// ---------------------------------------------------------------------------
extern "C" void kernel_launch(void* const* d_in, const int* in_sizes, int n_in,
                              void* d_out, int out_size, void* d_ws, size_t ws_size,
                              hipStream_t stream)
{
    const int*   input_step  = (const int*)  d_in[0];
    const float* last_hidden = (const float*)d_in[1];
    const float* enc         = (const float*)d_in[2];
    const float* emb         = (const float*)d_in[3];
    const float* w_ih0       = (const float*)d_in[4];
    const float* w_hh0       = (const float*)d_in[5];
    const float* b_ih0       = (const float*)d_in[6];
    const float* b_hh0       = (const float*)d_in[7];
    const float* w_ih1       = (const float*)d_in[8];
    const float* w_hh1       = (const float*)d_in[9];
    const float* b_ih1       = (const float*)d_in[10];
    const float* b_hh1       = (const float*)d_in[11];
    const float* concat_w    = (const float*)d_in[12];
    const float* concat_b    = (const float*)d_in[13];
    const float* out_w       = (const float*)d_in[14];
    const float* out_b       = (const float*)d_in[15];

    float* out = (float*)d_out;
    float* out_probs  = out;
    float* out_hidden = out + (size_t)BATCH * VOCAB;

    // Workspace layout (floats), with aliasing over the "big" region:
    //   big[0 .. 2359296): pgi0(786432)+pgh0(786432)+pgh1(786432)
    //     later: pgi1 (1572864, after gate0 consumed pgi0/pgh0; pgh1 untouched)
    //     later: pctx (2097152, after gate1)   later: pco (524288, after comb)
    float* ws   = (float*)d_ws;
    float* big  = ws;
    float* pgi0 = big;
    float* pgh0 = big + 786432;
    float* pgh1 = big + 1572864;
    float* pgi1 = big;              // alias (8 splits * 196608 = 1572864)
    float* pctx = big;              // alias (32 * 65536 = 2097152)
    float* pco  = big;              // alias (8 * 65536 = 524288)
    float* logits = ws + 2359296;                   // 64*LOGITS_LD = 3219456
    float* ci   = logits + (size_t)64 * LOGITS_LD;  // 131072
    float* h0   = ci + 131072;                      // 65536
    float* co   = h0 + 65536;                       // 65536
    float* pm   = co + 65536;                       // 2048
    float* ps   = pm + 2048;                        // 2048
    float* vmax = ps + 2048;                        // 512
    float* vsum = vmax + 512;                       // 512

    Prob P0 = { emb,         input_step, w_ih0, nullptr, pgi0, 3 * HID, EMB, 3 * HID };
    Prob P1 = { last_hidden, nullptr,    w_hh0, nullptr, pgh0, 3 * HID, HID, 3 * HID };
    Prob P2 = { last_hidden + 64 * HID, nullptr, w_hh1, nullptr, pgh1, 3 * HID, HID, 3 * HID };

    // 1. triple GEMM: gi0 (emb-gather), gh0, gh1 — all independent. split-K 4.
    gemm_k<256, 0><<<dim3(96, 3, 4), 128, 0, stream>>>(P0, P1, P2);

    // 2. gate layer 0 -> h0 (fp32), out_hidden[0]
    gru_gate_k<4, 4><<<256, 256, 0, stream>>>(pgi0, pgh0, b_ih0, b_hh0, last_hidden,
                                              out_hidden, h0, nullptr);

    // 3. gi1 = h0 @ w_ih1, split-K 8 (768 blocks)
    Prob PB = { h0, nullptr, w_ih1, nullptr, pgi1, 3 * HID, HID, 3 * HID };
    gemm_k<128, 0><<<dim3(96, 1, 8), 128, 0, stream>>>(PB, PB, PB);

    // 4. gate layer 1 -> out_hidden[1], ci[:, :1024]
    gru_gate_k<8, 4><<<256, 256, 0, stream>>>(pgi1, pgh1, b_ih1, b_hh1,
                                              last_hidden + 64 * HID,
                                              out_hidden + 64 * HID, nullptr, ci);

    // 5. attention: single-pass flash over 32 chunks of 16, then combine
    attn_fused_k<<<dim3(NCHUNK, BATCH), 256, 0, stream>>>(
        out_hidden + 64 * HID, enc, pctx, pm, ps);
    attn_comb_k<<<BATCH, 256, 0, stream>>>(pctx, pm, ps, ci);

    // 6. concat projection: split-K 8 + tanh combine
    Prob PC = { ci, nullptr, concat_w, nullptr, pco, HID, 2 * HID, HID };
    gemm_k<256, 0><<<dim3(32, 1, 8), 128, 0, stream>>>(PC, PC, PC);
    concat_comb_k<<<256, 256, 0, stream>>>(pco, concat_b, co);

    // 7. logits GEMM: 1571 32-col blocks, full K, bias fused
    Prob PL = { co, nullptr, out_w, out_b, logits, VOCAB, HID, LOGITS_LD };
    gemm_k<1024, 1><<<dim3((VOCAB + 31) / 32, 1, 1), 128, 0, stream>>>(PL, PL, PL);

    // 8. vocab softmax
    stats_part_k<<<dim3(8, BATCH), 256, 0, stream>>>(logits, vmax, vsum, LOGITS_LD);
    softmax_v_k<<<dim3((VOCAB + 1023) / 1024, BATCH), 256, 0, stream>>>(
        logits, vmax, vsum, out_probs, LOGITS_LD);
}

// Round 6
// 201.690 us; speedup vs baseline: 1.2135x; 1.2135x over previous
//
#include <hip/hip_runtime.h>
#include <hip/hip_bf16.h>
#include <math.h>

#define VOCAB 50257
#define EMB   1024
#define HID   1024
#define BATCH 64
#define SEQ   512
#define LOGITS_LD 50304
#define SCH   16                  // s-rows per attention chunk
#define NCHUNK (SEQ / SCH)        // 32

typedef __attribute__((ext_vector_type(8))) short bf16x8;
typedef __attribute__((ext_vector_type(4))) float f32x4;

__device__ inline short f2bf(float x) {
    __hip_bfloat16 h = __float2bfloat16(x);
    return *reinterpret_cast<short*>(&h);
}

__device__ inline bf16x8 cvt8(const float4& a, const float4& b) {
    bf16x8 r;
    r[0] = f2bf(a.x); r[1] = f2bf(a.y); r[2] = f2bf(a.z); r[3] = f2bf(a.w);
    r[4] = f2bf(b.x); r[5] = f2bf(b.y); r[6] = f2bf(b.z); r[7] = f2bf(b.w);
    return r;
}

// ---------------------------------------------------------------------------
// Direct-stream MFMA GEMM, up to 3 problems (blockIdx.y), split-K (blockIdx.z).
// 128 threads = 2 waves; wave = 16 cols x 64 rows; block tile = 32 cols.
// Depth-2 register double-buffer prefetch; __launch_bounds__(128,2) allows
// up to 256 VGPRs so the prefetch actually lives in registers.
// A: fp32 (A_BF16=0, converted in-flight) or bf16 (A_BF16=1).
// W: fp32 streamed, converted in-flight.
// ---------------------------------------------------------------------------
struct Prob {
    const void*  A;      // [64][K] fp32 or bf16
    const int*   gidx;   // optional row gather (embedding), else null
    const float* W;      // [N][K] fp32
    const float* bias;   // [N] (only if ADD_BIAS)
    float*       C;      // [nsplit][64][ldc]
    int N, K, ldc;
};

template <int KSLEN, int ADD_BIAS, int A_BF16>
__global__ __launch_bounds__(128, 2) void gemm_k(Prob p0, Prob p1, Prob p2)
{
    Prob P = (blockIdx.y == 0) ? p0 : ((blockIdx.y == 1) ? p1 : p2);

    const int lane = threadIdx.x & 63;
    const int wv   = threadIdx.x >> 6;     // 0..1
    const int rowi = lane & 15;
    const int kgi  = lane >> 4;            // 0..3
    const int col  = blockIdx.x * 32 + wv * 16 + rowi;
    const int wcol = min(col, P.N - 1);
    const int kbase = blockIdx.z * KSLEN + kgi * 8;

    const float* wp = P.W + (size_t)wcol * P.K + kbase;

    const float*  af[4];
    const ushort* ah[4];
#pragma unroll
    for (int mt = 0; mt < 4; ++mt) {
        int r  = rowi + mt * 16;
        int ar = P.gidx ? P.gidx[r] : r;
        af[mt] = (const float*) P.A + (size_t)ar * P.K + kbase;
        ah[mt] = (const ushort*)P.A + (size_t)ar * P.K + kbase;
    }

    f32x4 acc[4] = {};

    // double-buffer registers (named, static — no scratch)
    float4 wa0, wb0, wa1, wb1;
    bf16x8 h0b[4], h1b[4];
    float4 f0a[4], f0b[4], f1a[4], f1b[4];

    // prologue: buf0 <- ks=0, buf1 <- ks=32   (KSLEN >= 64 always)
    wa0 = *(const float4*)(wp);
    wb0 = *(const float4*)(wp + 4);
#pragma unroll
    for (int mt = 0; mt < 4; ++mt) {
        if (A_BF16) h0b[mt] = *(const bf16x8*)(ah[mt]);
        else { f0a[mt] = *(const float4*)(af[mt]); f0b[mt] = *(const float4*)(af[mt] + 4); }
    }
    wa1 = *(const float4*)(wp + 32);
    wb1 = *(const float4*)(wp + 36);
#pragma unroll
    for (int mt = 0; mt < 4; ++mt) {
        if (A_BF16) h1b[mt] = *(const bf16x8*)(ah[mt] + 32);
        else { f1a[mt] = *(const float4*)(af[mt] + 32); f1b[mt] = *(const float4*)(af[mt] + 36); }
    }

#pragma unroll
    for (int ks = 0; ks < KSLEN; ks += 64) {
        // ---- even step: consume buf0 @ks, prefetch ks+64 -> buf0 ----
        {
            float4 nwa = {}, nwb = {};
            bf16x8 nh[4] = {};
            float4 nfa[4] = {}, nfb[4] = {};
            if (ks + 64 < KSLEN) {
                nwa = *(const float4*)(wp + ks + 64);
                nwb = *(const float4*)(wp + ks + 68);
#pragma unroll
                for (int mt = 0; mt < 4; ++mt) {
                    if (A_BF16) nh[mt] = *(const bf16x8*)(ah[mt] + ks + 64);
                    else { nfa[mt] = *(const float4*)(af[mt] + ks + 64);
                           nfb[mt] = *(const float4*)(af[mt] + ks + 68); }
                }
            }
            bf16x8 b = cvt8(wa0, wb0);
#pragma unroll
            for (int mt = 0; mt < 4; ++mt) {
                bf16x8 a;
                if (A_BF16) a = h0b[mt]; else a = cvt8(f0a[mt], f0b[mt]);
                acc[mt] = __builtin_amdgcn_mfma_f32_16x16x32_bf16(a, b, acc[mt], 0, 0, 0);
            }
            wa0 = nwa; wb0 = nwb;
#pragma unroll
            for (int mt = 0; mt < 4; ++mt) {
                if (A_BF16) h0b[mt] = nh[mt];
                else { f0a[mt] = nfa[mt]; f0b[mt] = nfb[mt]; }
            }
        }
        // ---- odd step: consume buf1 @ks+32, prefetch ks+96 -> buf1 ----
        {
            float4 nwa = {}, nwb = {};
            bf16x8 nh[4] = {};
            float4 nfa[4] = {}, nfb[4] = {};
            if (ks + 96 < KSLEN) {
                nwa = *(const float4*)(wp + ks + 96);
                nwb = *(const float4*)(wp + ks + 100);
#pragma unroll
                for (int mt = 0; mt < 4; ++mt) {
                    if (A_BF16) nh[mt] = *(const bf16x8*)(ah[mt] + ks + 96);
                    else { nfa[mt] = *(const float4*)(af[mt] + ks + 96);
                           nfb[mt] = *(const float4*)(af[mt] + ks + 100); }
                }
            }
            bf16x8 b = cvt8(wa1, wb1);
#pragma unroll
            for (int mt = 0; mt < 4; ++mt) {
                bf16x8 a;
                if (A_BF16) a = h1b[mt]; else a = cvt8(f1a[mt], f1b[mt]);
                acc[mt] = __builtin_amdgcn_mfma_f32_16x16x32_bf16(a, b, acc[mt], 0, 0, 0);
            }
            wa1 = nwa; wb1 = nwb;
#pragma unroll
            for (int mt = 0; mt < 4; ++mt) {
                if (A_BF16) h1b[mt] = nh[mt];
                else { f1a[mt] = nfa[mt]; f1b[mt] = nfb[mt]; }
            }
        }
    }

    if (col < P.N) {
        float bv = ADD_BIAS ? P.bias[col] : 0.0f;
        float* C = P.C + (size_t)blockIdx.z * 64 * P.ldc;
#pragma unroll
        for (int mt = 0; mt < 4; ++mt)
#pragma unroll
            for (int r = 0; r < 4; ++r) {
                int row = mt * 16 + kgi * 4 + r;
                C[(size_t)row * P.ldc + col] = acc[mt][r] + bv;
            }
    }
}

// ---------------------------------------------------------------------------
// GRU gate fusion over split-K partials (NZI for gi, NZH for gh).
// ---------------------------------------------------------------------------
template <int NZI, int NZH>
__global__ __launch_bounds__(256) void gru_gate_k(
    const float* __restrict__ pgi, const float* __restrict__ pgh,
    const float* __restrict__ b_ih, const float* __restrict__ b_hh,
    const float* __restrict__ hprev, float* __restrict__ out_hidden,
    float* __restrict__ h_out, float* __restrict__ ci)
{
    int i = blockIdx.x * 256 + threadIdx.x;   // 0 .. 65536
    int b = i >> 10, j = i & 1023;
    size_t base = (size_t)b * 3072 + j;
    float ir = b_ih[j], iz = b_ih[j + 1024], in_ = b_ih[j + 2048];
    float hr = b_hh[j], hz = b_hh[j + 1024], hn  = b_hh[j + 2048];
#pragma unroll
    for (int z = 0; z < NZI; ++z) {
        size_t o = (size_t)z * 64 * 3072 + base;
        ir += pgi[o]; iz += pgi[o + 1024]; in_ += pgi[o + 2048];
    }
#pragma unroll
    for (int z = 0; z < NZH; ++z) {
        size_t o = (size_t)z * 64 * 3072 + base;
        hr += pgh[o]; hz += pgh[o + 1024]; hn  += pgh[o + 2048];
    }
    float r = 1.0f / (1.0f + expf(-(ir + hr)));
    float z = 1.0f / (1.0f + expf(-(iz + hz)));
    float n = tanhf(in_ + r * hn);
    float v = (1.0f - z) * n + z * hprev[i];
    out_hidden[i] = v;
    if (h_out) h_out[i] = v;
    if (ci)    ci[(size_t)b * 2048 + j] = v;
}

// ---------------------------------------------------------------------------
// Single-pass flash attention chunk: per (chunk of 16 s, b).
// ---------------------------------------------------------------------------
__global__ __launch_bounds__(256) void attn_fused_k(
    const float* __restrict__ h1, const float* __restrict__ enc,
    float* __restrict__ pctx, float* __restrict__ pm, float* __restrict__ ps)
{
    const int b = blockIdx.y, ck = blockIdx.x;
    __shared__ float hs[HID];
    __shared__ float es[SCH][HID];
    __shared__ float sc[SCH];
    const int tid = threadIdx.x, wv = tid >> 6, lane = tid & 63;

    ((float4*)hs)[tid] = ((const float4*)(h1 + (size_t)b * HID))[tid];
    const float* ebase = enc + ((size_t)(ck * SCH) * BATCH + b) * HID;
#pragma unroll
    for (int i = 0; i < SCH; ++i) {
        int idx = tid + i * 256;
        int r = idx >> 8, c = idx & 255;
        ((float4*)es[r])[c] = ((const float4*)(ebase + (size_t)r * BATCH * HID))[c];
    }
    __syncthreads();

#pragma unroll
    for (int i = 0; i < 4; ++i) {
        int r = wv * 4 + i;
        float acc = 0.0f;
#pragma unroll
        for (int seg = 0; seg < 4; ++seg) {
            float4 ev = ((const float4*)es[r])[lane + seg * 64];
            float4 hv = ((const float4*)hs)[lane + seg * 64];
            acc += ev.x * hv.x + ev.y * hv.y + ev.z * hv.z + ev.w * hv.w;
        }
        for (int off = 32; off; off >>= 1) acc += __shfl_down(acc, off);
        if (lane == 0) sc[r] = acc;
    }
    __syncthreads();

    float m = sc[0];
#pragma unroll
    for (int s = 1; s < SCH; ++s) m = fmaxf(m, sc[s]);
    float p[SCH];
    float sum = 0.0f;
#pragma unroll
    for (int s = 0; s < SCH; ++s) { p[s] = expf(sc[s] - m); sum += p[s]; }

    float4 cacc = {0.0f, 0.0f, 0.0f, 0.0f};
#pragma unroll
    for (int s = 0; s < SCH; ++s) {
        float4 ev = ((const float4*)es[s])[tid];
        cacc.x += p[s] * ev.x; cacc.y += p[s] * ev.y;
        cacc.z += p[s] * ev.z; cacc.w += p[s] * ev.w;
    }
    ((float4*)(pctx + ((size_t)ck * BATCH + b) * HID))[tid] = cacc;
    if (tid == 0) { pm[b * NCHUNK + ck] = m; ps[b * NCHUNK + ck] = sum; }
}

// ---------------------------------------------------------------------------
// Attention combine: merge 32 chunk partials -> ci[:,1024:] (fp32)
// ---------------------------------------------------------------------------
__global__ __launch_bounds__(256) void attn_comb_k(
    const float* __restrict__ pctx, const float* __restrict__ pm,
    const float* __restrict__ ps, float* __restrict__ ci)
{
    const int b = blockIdx.x, tid = threadIdx.x;
    float m = -INFINITY;
#pragma unroll
    for (int c = 0; c < NCHUNK; ++c) m = fmaxf(m, pm[b * NCHUNK + c]);
    float w[NCHUNK]; float tot = 0.0f;
#pragma unroll
    for (int c = 0; c < NCHUNK; ++c) {
        w[c] = expf(pm[b * NCHUNK + c] - m);
        tot += ps[b * NCHUNK + c] * w[c];
    }
    float inv = 1.0f / tot;
    float4 acc = {0.0f, 0.0f, 0.0f, 0.0f};
#pragma unroll
    for (int c = 0; c < NCHUNK; ++c) {
        float4 v = ((const float4*)(pctx + ((size_t)c * BATCH + b) * HID))[tid];
        acc.x += w[c] * v.x; acc.y += w[c] * v.y;
        acc.z += w[c] * v.z; acc.w += w[c] * v.w;
    }
    float4 o = {acc.x * inv, acc.y * inv, acc.z * inv, acc.w * inv};
    ((float4*)(ci + (size_t)b * 2048 + 1024))[tid] = o;
}

// ---------------------------------------------------------------------------
// Concat combine: co_bf = bf16(tanh(sum of 8 partials + bias))
// ---------------------------------------------------------------------------
__global__ __launch_bounds__(256) void concat_comb_k(
    const float* __restrict__ pco, const float* __restrict__ bias,
    ushort* __restrict__ co_bf)
{
    int i = blockIdx.x * 256 + threadIdx.x;
    int j = i & 1023;
    float v = bias[j];
#pragma unroll
    for (int z = 0; z < 8; ++z) v += pco[(size_t)z * 65536 + i];
    co_bf[i] = (ushort)f2bf(tanhf(v));
}

// ---------------------------------------------------------------------------
// Partial logit stats per (b, 1/8 of VOCAB)
// ---------------------------------------------------------------------------
#define VCHUNK 6284
__global__ __launch_bounds__(256) void stats_part_k(
    const float* __restrict__ logits, float* __restrict__ vmax,
    float* __restrict__ vsum, int ldc)
{
    int b = blockIdx.y, ch = blockIdx.x;
    int v0 = ch * VCHUNK;
    int v1 = min(v0 + VCHUNK, VOCAB);
    const float* row = logits + (size_t)b * ldc;
    float m = -INFINITY;
    for (int v = v0 + threadIdx.x; v < v1; v += 256) m = fmaxf(m, row[v]);
    __shared__ float red[4];
    for (int off = 32; off; off >>= 1) m = fmaxf(m, __shfl_xor(m, off));
    int wave = threadIdx.x >> 6, lane = threadIdx.x & 63;
    if (lane == 0) red[wave] = m;
    __syncthreads();
    m = fmaxf(fmaxf(red[0], red[1]), fmaxf(red[2], red[3]));
    float ssum = 0.0f;
    for (int v = v0 + threadIdx.x; v < v1; v += 256) ssum += expf(row[v] - m);
    for (int off = 32; off; off >>= 1) ssum += __shfl_xor(ssum, off);
    __syncthreads();
    if (lane == 0) red[wave] = ssum;
    __syncthreads();
    if (threadIdx.x == 0) {
        vmax[b * 8 + ch] = m;
        vsum[b * 8 + ch] = red[0] + red[1] + red[2] + red[3];
    }
}

// ---------------------------------------------------------------------------
// Softmax normalize over VOCAB
// ---------------------------------------------------------------------------
__global__ __launch_bounds__(256) void softmax_v_k(
    const float* __restrict__ logits, const float* __restrict__ vmax,
    const float* __restrict__ vsum, float* __restrict__ out, int ldc)
{
    int b = blockIdx.y;
    float m = -INFINITY;
#pragma unroll
    for (int i = 0; i < 8; ++i) m = fmaxf(m, vmax[b * 8 + i]);
    float tot = 0.0f;
#pragma unroll
    for (int i = 0; i < 8; ++i) tot += vsum[b * 8 + i] * expf(vmax[b * 8 + i] - m);
    float inv = 1.0f / tot;
    int v = blockIdx.x * 1024 + threadIdx.x * 4;
    if (v + 3 < VOCAB) {
        float4 lv = *reinterpret_cast<const float4*>(logits + (size_t)b * ldc + v);
        float4 o;
        o.x = expf(lv.x - m) * inv; o.y = expf(lv.y - m) * inv;
        o.z = expf(lv.z - m) * inv; o.w = expf(lv.w - m) * inv;
        *reinterpret_cast<float4*>(out + (size_t)b * VOCAB + v) = o;
    } else {
        for (int k = 0; k < 4 && v + k < VOCAB; ++k)
            out[(size_t)b * VOCAB + v + k] = expf(logits[(size_t)b * ldc + v + k] - m) * inv;
    }
}

// ---------------------------------------------------------------------------
extern "C" void kernel_launch(void* const* d_in, const int* in_sizes, int n_in,
                              void* d_out, int out_size, void* d_ws, size_t ws_size,
                              hipStream_t stream)
{
    const int*   input_step  = (const int*)  d_in[0];
    const float* last_hidden = (const float*)d_in[1];
    const float* enc         = (const float*)d_in[2];
    const float* emb         = (const float*)d_in[3];
    const float* w_ih0       = (const float*)d_in[4];
    const float* w_hh0       = (const float*)d_in[5];
    const float* b_ih0       = (const float*)d_in[6];
    const float* b_hh0       = (const float*)d_in[7];
    const float* w_ih1       = (const float*)d_in[8];
    const float* w_hh1       = (const float*)d_in[9];
    const float* b_ih1       = (const float*)d_in[10];
    const float* b_hh1       = (const float*)d_in[11];
    const float* concat_w    = (const float*)d_in[12];
    const float* concat_b    = (const float*)d_in[13];
    const float* out_w       = (const float*)d_in[14];
    const float* out_b       = (const float*)d_in[15];

    float* out = (float*)d_out;
    float* out_probs  = out;
    float* out_hidden = out + (size_t)BATCH * VOCAB;

    // Workspace layout (floats), aliasing over the "big" region:
    //   big: pgi0(786432)+pgh0(786432)+pgh1(786432)
    //     later: pgi1 (8*196608, after gate0; pgh1 beyond untouched)
    //     later: pctx (32*65536, after gate1)   later: pco (8*65536)
    float* ws   = (float*)d_ws;
    float* big  = ws;
    float* pgi0 = big;
    float* pgh0 = big + 786432;
    float* pgh1 = big + 1572864;
    float* pgi1 = big;              // alias
    float* pctx = big;              // alias
    float* pco  = big;              // alias
    float* logits = ws + 2359296;                   // 64*LOGITS_LD
    float* ci   = logits + (size_t)64 * LOGITS_LD;  // 131072
    float* h0   = ci + 131072;                      // 65536
    float* pm   = h0 + 65536;                       // 2048
    float* ps   = pm + 2048;                        // 2048
    float* vmax = ps + 2048;                        // 512
    float* vsum = vmax + 512;                       // 512
    ushort* co_bf = (ushort*)(vsum + 512);          // 65536 ushorts

    Prob P0 = { emb,         input_step, w_ih0, nullptr, pgi0, 3 * HID, EMB, 3 * HID };
    Prob P1 = { last_hidden, nullptr,    w_hh0, nullptr, pgh0, 3 * HID, HID, 3 * HID };
    Prob P2 = { last_hidden + 64 * HID, nullptr, w_hh1, nullptr, pgh1, 3 * HID, HID, 3 * HID };

    // 1. triple GEMM: gi0 (emb-gather), gh0, gh1 — independent. split-K 4.
    gemm_k<256, 0, 0><<<dim3(96, 3, 4), 128, 0, stream>>>(P0, P1, P2);

    // 2. gate layer 0 -> h0 (fp32), out_hidden[0]
    gru_gate_k<4, 4><<<256, 256, 0, stream>>>(pgi0, pgh0, b_ih0, b_hh0, last_hidden,
                                              out_hidden, h0, nullptr);

    // 3. gi1 = h0 @ w_ih1, split-K 8
    Prob PB = { h0, nullptr, w_ih1, nullptr, pgi1, 3 * HID, HID, 3 * HID };
    gemm_k<128, 0, 0><<<dim3(96, 1, 8), 128, 0, stream>>>(PB, PB, PB);

    // 4. gate layer 1 -> out_hidden[1], ci[:, :1024]
    gru_gate_k<8, 4><<<256, 256, 0, stream>>>(pgi1, pgh1, b_ih1, b_hh1,
                                              last_hidden + 64 * HID,
                                              out_hidden + 64 * HID, nullptr, ci);

    // 5. attention: single-pass flash over 32 chunks of 16, then combine
    attn_fused_k<<<dim3(NCHUNK, BATCH), 256, 0, stream>>>(
        out_hidden + 64 * HID, enc, pctx, pm, ps);
    attn_comb_k<<<BATCH, 256, 0, stream>>>(pctx, pm, ps, ci);

    // 6. concat projection: split-K 8 + tanh combine -> co_bf (bf16)
    Prob PC = { ci, nullptr, concat_w, nullptr, pco, HID, 2 * HID, HID };
    gemm_k<256, 0, 0><<<dim3(32, 1, 8), 128, 0, stream>>>(PC, PC, PC);
    concat_comb_k<<<256, 256, 0, stream>>>(pco, concat_b, co_bf);

    // 7. logits GEMM: bf16 A, full K, bias fused, depth-2 prefetch
    Prob PL = { co_bf, nullptr, out_w, out_b, logits, VOCAB, HID, LOGITS_LD };
    gemm_k<1024, 1, 1><<<dim3((VOCAB + 31) / 32, 1, 1), 128, 0, stream>>>(PL, PL, PL);

    // 8. vocab softmax
    stats_part_k<<<dim3(8, BATCH), 256, 0, stream>>>(logits, vmax, vsum, LOGITS_LD);
    softmax_v_k<<<dim3((VOCAB + 1023) / 1024, BATCH), 256, 0, stream>>>(
        logits, vmax, vsum, out_probs, LOGITS_LD);
}

// Round 7
// 196.904 us; speedup vs baseline: 1.2430x; 1.0243x over previous
//
#include <hip/hip_runtime.h>
#include <hip/hip_bf16.h>
#include <math.h>

#define VOCAB 50257
#define EMB   1024
#define HID   1024
#define BATCH 64
#define SEQ   512
#define LOGITS_LD 50304
#define SCH   16                  // s-rows per attention chunk
#define NCHUNK (SEQ / SCH)        // 32

typedef __attribute__((ext_vector_type(8))) short bf16x8;
typedef __attribute__((ext_vector_type(4))) float f32x4;

typedef const __attribute__((address_space(1))) unsigned int gu32_t;
typedef __attribute__((address_space(3))) unsigned int lu32_t;

__device__ inline short f2bf(float x) {
    __hip_bfloat16 h = __float2bfloat16(x);
    return *reinterpret_cast<short*>(&h);
}

__device__ inline bf16x8 cvt8(const float4& a, const float4& b) {
    bf16x8 r;
    r[0] = f2bf(a.x); r[1] = f2bf(a.y); r[2] = f2bf(a.z); r[3] = f2bf(a.w);
    r[4] = f2bf(b.x); r[5] = f2bf(b.y); r[6] = f2bf(b.z); r[7] = f2bf(b.w);
    return r;
}

// ---------------------------------------------------------------------------
// Direct-stream MFMA GEMM for the small GEMMs (unchanged from round 6).
// ---------------------------------------------------------------------------
struct Prob {
    const void*  A;
    const int*   gidx;
    const float* W;
    const float* bias;
    float*       C;
    int N, K, ldc;
};

template <int KSLEN, int ADD_BIAS, int A_BF16>
__global__ __launch_bounds__(128, 2) void gemm_k(Prob p0, Prob p1, Prob p2)
{
    Prob P = (blockIdx.y == 0) ? p0 : ((blockIdx.y == 1) ? p1 : p2);

    const int lane = threadIdx.x & 63;
    const int wv   = threadIdx.x >> 6;
    const int rowi = lane & 15;
    const int kgi  = lane >> 4;
    const int col  = blockIdx.x * 32 + wv * 16 + rowi;
    const int wcol = min(col, P.N - 1);
    const int kbase = blockIdx.z * KSLEN + kgi * 8;

    const float* wp = P.W + (size_t)wcol * P.K + kbase;

    const float*  af[4];
    const ushort* ah[4];
#pragma unroll
    for (int mt = 0; mt < 4; ++mt) {
        int r  = rowi + mt * 16;
        int ar = P.gidx ? P.gidx[r] : r;
        af[mt] = (const float*) P.A + (size_t)ar * P.K + kbase;
        ah[mt] = (const ushort*)P.A + (size_t)ar * P.K + kbase;
    }

    f32x4 acc[4] = {};

    float4 wa0, wb0, wa1, wb1;
    bf16x8 h0b[4], h1b[4];
    float4 f0a[4], f0b[4], f1a[4], f1b[4];

    wa0 = *(const float4*)(wp);
    wb0 = *(const float4*)(wp + 4);
#pragma unroll
    for (int mt = 0; mt < 4; ++mt) {
        if (A_BF16) h0b[mt] = *(const bf16x8*)(ah[mt]);
        else { f0a[mt] = *(const float4*)(af[mt]); f0b[mt] = *(const float4*)(af[mt] + 4); }
    }
    wa1 = *(const float4*)(wp + 32);
    wb1 = *(const float4*)(wp + 36);
#pragma unroll
    for (int mt = 0; mt < 4; ++mt) {
        if (A_BF16) h1b[mt] = *(const bf16x8*)(ah[mt] + 32);
        else { f1a[mt] = *(const float4*)(af[mt] + 32); f1b[mt] = *(const float4*)(af[mt] + 36); }
    }

#pragma unroll
    for (int ks = 0; ks < KSLEN; ks += 64) {
        {
            float4 nwa = {}, nwb = {};
            bf16x8 nh[4] = {};
            float4 nfa[4] = {}, nfb[4] = {};
            if (ks + 64 < KSLEN) {
                nwa = *(const float4*)(wp + ks + 64);
                nwb = *(const float4*)(wp + ks + 68);
#pragma unroll
                for (int mt = 0; mt < 4; ++mt) {
                    if (A_BF16) nh[mt] = *(const bf16x8*)(ah[mt] + ks + 64);
                    else { nfa[mt] = *(const float4*)(af[mt] + ks + 64);
                           nfb[mt] = *(const float4*)(af[mt] + ks + 68); }
                }
            }
            bf16x8 b = cvt8(wa0, wb0);
#pragma unroll
            for (int mt = 0; mt < 4; ++mt) {
                bf16x8 a;
                if (A_BF16) a = h0b[mt]; else a = cvt8(f0a[mt], f0b[mt]);
                acc[mt] = __builtin_amdgcn_mfma_f32_16x16x32_bf16(a, b, acc[mt], 0, 0, 0);
            }
            wa0 = nwa; wb0 = nwb;
#pragma unroll
            for (int mt = 0; mt < 4; ++mt) {
                if (A_BF16) h0b[mt] = nh[mt];
                else { f0a[mt] = nfa[mt]; f0b[mt] = nfb[mt]; }
            }
        }
        {
            float4 nwa = {}, nwb = {};
            bf16x8 nh[4] = {};
            float4 nfa[4] = {}, nfb[4] = {};
            if (ks + 96 < KSLEN) {
                nwa = *(const float4*)(wp + ks + 96);
                nwb = *(const float4*)(wp + ks + 100);
#pragma unroll
                for (int mt = 0; mt < 4; ++mt) {
                    if (A_BF16) nh[mt] = *(const bf16x8*)(ah[mt] + ks + 96);
                    else { nfa[mt] = *(const float4*)(af[mt] + ks + 96);
                           nfb[mt] = *(const float4*)(af[mt] + ks + 100); }
                }
            }
            bf16x8 b = cvt8(wa1, wb1);
#pragma unroll
            for (int mt = 0; mt < 4; ++mt) {
                bf16x8 a;
                if (A_BF16) a = h1b[mt]; else a = cvt8(f1a[mt], f1b[mt]);
                acc[mt] = __builtin_amdgcn_mfma_f32_16x16x32_bf16(a, b, acc[mt], 0, 0, 0);
            }
            wa1 = nwa; wb1 = nwb;
#pragma unroll
            for (int mt = 0; mt < 4; ++mt) {
                if (A_BF16) h1b[mt] = nh[mt];
                else { f1a[mt] = nfa[mt]; f1b[mt] = nfb[mt]; }
            }
        }
    }

    if (col < P.N) {
        float bv = ADD_BIAS ? P.bias[col] : 0.0f;
        float* C = P.C + (size_t)blockIdx.z * 64 * P.ldc;
#pragma unroll
        for (int mt = 0; mt < 4; ++mt)
#pragma unroll
            for (int r = 0; r < 4; ++r) {
                int row = mt * 16 + kgi * 4 + r;
                C[(size_t)row * P.ldc + col] = acc[mt][r] + bv;
            }
    }
}

// ---------------------------------------------------------------------------
// Logits GEMM: W-as-A orientation (vocab rows = MFMA A rows).
// 2-phase global_load_lds pipeline, 64 vocab rows / block, K-chunks of 64.
// LDS: double-buffered 16 KB W chunks, XOR-swizzled via pre-swizzled SOURCE
// (LDS dest linear — rule 21). co (bf16, L2-broadcast) double-buffered in regs.
// ---------------------------------------------------------------------------
__global__ __launch_bounds__(256, 3) void logits_k(
    const ushort* __restrict__ co_bf, const float* __restrict__ W,
    const float* __restrict__ bias, float* __restrict__ logits)
{
    __shared__ float lds[2][4096];            // [buf][64 rows * 64 floats]
    const int tid  = threadIdx.x;
    const int lane = tid & 63;
    const int wv   = tid >> 6;
    const int rowi = lane & 15;
    const int kgi  = lane >> 4;
    const int nblk = blockIdx.x * 64;

    // staging source precompute (4 gload_lds rounds of 4 KB each)
    size_t srcbase[4];
    int    ldsoff[4];
#pragma unroll
    for (int j = 0; j < 4; ++j) {
        int o     = j * 4096 + tid * 16;              // linear LDS byte offset
        int row   = o >> 8;                           // 256 B per row
        int inner = (o & 255) ^ ((row & 7) << 5);     // inverse swizzle on src
        int grow  = min(nblk + row, VOCAB - 1);
        srcbase[j] = (size_t)grow * 1024 + (inner >> 2);   // float index
        ldsoff[j]  = (j * 4096 + wv * 1024) >> 2;          // wave-uniform, floats
    }

    const ushort* cop = co_bf + (size_t)rowi * 1024 + kgi * 8;  // cf adds 16*1024

    f32x4 acc[4] = {};
    bf16x8 co[2][8];   // [buf][cf*2+ks]

    // ---- prologue: stage chunk 0 + co chunk 0
#pragma unroll
    for (int j = 0; j < 4; ++j)
        __builtin_amdgcn_global_load_lds((gu32_t*)(W + srcbase[j]),
                                         (lu32_t*)&lds[0][ldsoff[j]], 16, 0, 0);
#pragma unroll
    for (int cf = 0; cf < 4; ++cf)
#pragma unroll
        for (int ks = 0; ks < 2; ++ks)
            co[0][cf * 2 + ks] = *(const bf16x8*)(cop + (size_t)cf * 16 * 1024 + ks * 32);
    __syncthreads();

    const int rloc = wv * 16 + rowi;
    const int swz  = (rloc & 7) << 5;

#pragma unroll
    for (int t = 0; t < 16; ++t) {
        const int cur = t & 1, nxt = cur ^ 1;
        if (t + 1 < 16) {
#pragma unroll
            for (int j = 0; j < 4; ++j)
                __builtin_amdgcn_global_load_lds(
                    (gu32_t*)(W + srcbase[j] + (t + 1) * 64),
                    (lu32_t*)&lds[nxt][ldsoff[j]], 16, 0, 0);
#pragma unroll
            for (int cf = 0; cf < 4; ++cf)
#pragma unroll
                for (int ks = 0; ks < 2; ++ks)
                    co[nxt][cf * 2 + ks] = *(const bf16x8*)(
                        cop + (size_t)cf * 16 * 1024 + (t + 1) * 64 + ks * 32);
        }
        // compute chunk t from lds[cur]
#pragma unroll
        for (int ks = 0; ks < 2; ++ks) {
            const char* p = (const char*)&lds[cur][0] + rloc * 256 +
                            ((ks * 128 + kgi * 32) ^ swz);
            float4 wa = *(const float4*)p;
            float4 wb = *(const float4*)(p + 16);
            bf16x8 wf = cvt8(wa, wb);
#pragma unroll
            for (int cf = 0; cf < 4; ++cf)
                acc[cf] = __builtin_amdgcn_mfma_f32_16x16x32_bf16(
                    wf, co[cur][cf * 2 + ks], acc[cf], 0, 0, 0);
        }
        __syncthreads();
    }

    // epilogue: D row = vocab (kgi*4 + r), D col = batch (cf*16 + rowi)
    const int nb = nblk + wv * 16 + kgi * 4;
#pragma unroll
    for (int cf = 0; cf < 4; ++cf) {
        int b = cf * 16 + rowi;
        if (nb + 3 < VOCAB) {
            float4 bv = *(const float4*)(bias + nb);
            float4 o  = {acc[cf][0] + bv.x, acc[cf][1] + bv.y,
                         acc[cf][2] + bv.z, acc[cf][3] + bv.w};
            *(float4*)(logits + (size_t)b * LOGITS_LD + nb) = o;
        } else {
#pragma unroll
            for (int r = 0; r < 4; ++r)
                if (nb + r < VOCAB)
                    logits[(size_t)b * LOGITS_LD + nb + r] = acc[cf][r] + bias[nb + r];
        }
    }
}

// ---------------------------------------------------------------------------
// GRU gate fusion over split-K partials (NZI for gi, NZH for gh).
// ---------------------------------------------------------------------------
template <int NZI, int NZH>
__global__ __launch_bounds__(256) void gru_gate_k(
    const float* __restrict__ pgi, const float* __restrict__ pgh,
    const float* __restrict__ b_ih, const float* __restrict__ b_hh,
    const float* __restrict__ hprev, float* __restrict__ out_hidden,
    float* __restrict__ h_out, float* __restrict__ ci)
{
    int i = blockIdx.x * 256 + threadIdx.x;
    int b = i >> 10, j = i & 1023;
    size_t base = (size_t)b * 3072 + j;
    float ir = b_ih[j], iz = b_ih[j + 1024], in_ = b_ih[j + 2048];
    float hr = b_hh[j], hz = b_hh[j + 1024], hn  = b_hh[j + 2048];
#pragma unroll
    for (int z = 0; z < NZI; ++z) {
        size_t o = (size_t)z * 64 * 3072 + base;
        ir += pgi[o]; iz += pgi[o + 1024]; in_ += pgi[o + 2048];
    }
#pragma unroll
    for (int z = 0; z < NZH; ++z) {
        size_t o = (size_t)z * 64 * 3072 + base;
        hr += pgh[o]; hz += pgh[o + 1024]; hn  += pgh[o + 2048];
    }
    float r = 1.0f / (1.0f + expf(-(ir + hr)));
    float z = 1.0f / (1.0f + expf(-(iz + hz)));
    float n = tanhf(in_ + r * hn);
    float v = (1.0f - z) * n + z * hprev[i];
    out_hidden[i] = v;
    if (h_out) h_out[i] = v;
    if (ci)    ci[(size_t)b * 2048 + j] = v;
}

// ---------------------------------------------------------------------------
// Single-pass flash attention chunk: per (chunk of 16 s, b).
// ---------------------------------------------------------------------------
__global__ __launch_bounds__(256) void attn_fused_k(
    const float* __restrict__ h1, const float* __restrict__ enc,
    float* __restrict__ pctx, float* __restrict__ pm, float* __restrict__ ps)
{
    const int b = blockIdx.y, ck = blockIdx.x;
    __shared__ float hs[HID];
    __shared__ float es[SCH][HID];
    __shared__ float sc[SCH];
    const int tid = threadIdx.x, wv = tid >> 6, lane = tid & 63;

    ((float4*)hs)[tid] = ((const float4*)(h1 + (size_t)b * HID))[tid];
    const float* ebase = enc + ((size_t)(ck * SCH) * BATCH + b) * HID;
#pragma unroll
    for (int i = 0; i < SCH; ++i) {
        int idx = tid + i * 256;
        int r = idx >> 8, c = idx & 255;
        ((float4*)es[r])[c] = ((const float4*)(ebase + (size_t)r * BATCH * HID))[c];
    }
    __syncthreads();

#pragma unroll
    for (int i = 0; i < 4; ++i) {
        int r = wv * 4 + i;
        float acc = 0.0f;
#pragma unroll
        for (int seg = 0; seg < 4; ++seg) {
            float4 ev = ((const float4*)es[r])[lane + seg * 64];
            float4 hv = ((const float4*)hs)[lane + seg * 64];
            acc += ev.x * hv.x + ev.y * hv.y + ev.z * hv.z + ev.w * hv.w;
        }
        for (int off = 32; off; off >>= 1) acc += __shfl_down(acc, off);
        if (lane == 0) sc[r] = acc;
    }
    __syncthreads();

    float m = sc[0];
#pragma unroll
    for (int s = 1; s < SCH; ++s) m = fmaxf(m, sc[s]);
    float p[SCH];
    float sum = 0.0f;
#pragma unroll
    for (int s = 0; s < SCH; ++s) { p[s] = expf(sc[s] - m); sum += p[s]; }

    float4 cacc = {0.0f, 0.0f, 0.0f, 0.0f};
#pragma unroll
    for (int s = 0; s < SCH; ++s) {
        float4 ev = ((const float4*)es[s])[tid];
        cacc.x += p[s] * ev.x; cacc.y += p[s] * ev.y;
        cacc.z += p[s] * ev.z; cacc.w += p[s] * ev.w;
    }
    ((float4*)(pctx + ((size_t)ck * BATCH + b) * HID))[tid] = cacc;
    if (tid == 0) { pm[b * NCHUNK + ck] = m; ps[b * NCHUNK + ck] = sum; }
}

// ---------------------------------------------------------------------------
// Attention combine: merge 32 chunk partials -> ci[:,1024:] (fp32)
// ---------------------------------------------------------------------------
__global__ __launch_bounds__(256) void attn_comb_k(
    const float* __restrict__ pctx, const float* __restrict__ pm,
    const float* __restrict__ ps, float* __restrict__ ci)
{
    const int b = blockIdx.x, tid = threadIdx.x;
    float m = -INFINITY;
#pragma unroll
    for (int c = 0; c < NCHUNK; ++c) m = fmaxf(m, pm[b * NCHUNK + c]);
    float w[NCHUNK]; float tot = 0.0f;
#pragma unroll
    for (int c = 0; c < NCHUNK; ++c) {
        w[c] = expf(pm[b * NCHUNK + c] - m);
        tot += ps[b * NCHUNK + c] * w[c];
    }
    float inv = 1.0f / tot;
    float4 acc = {0.0f, 0.0f, 0.0f, 0.0f};
#pragma unroll
    for (int c = 0; c < NCHUNK; ++c) {
        float4 v = ((const float4*)(pctx + ((size_t)c * BATCH + b) * HID))[tid];
        acc.x += w[c] * v.x; acc.y += w[c] * v.y;
        acc.z += w[c] * v.z; acc.w += w[c] * v.w;
    }
    float4 o = {acc.x * inv, acc.y * inv, acc.z * inv, acc.w * inv};
    ((float4*)(ci + (size_t)b * 2048 + 1024))[tid] = o;
}

// ---------------------------------------------------------------------------
// Concat combine: co_bf = bf16(tanh(sum of 8 partials + bias))
// ---------------------------------------------------------------------------
__global__ __launch_bounds__(256) void concat_comb_k(
    const float* __restrict__ pco, const float* __restrict__ bias,
    ushort* __restrict__ co_bf)
{
    int i = blockIdx.x * 256 + threadIdx.x;
    int j = i & 1023;
    float v = bias[j];
#pragma unroll
    for (int z = 0; z < 8; ++z) v += pco[(size_t)z * 65536 + i];
    co_bf[i] = (ushort)f2bf(tanhf(v));
}

// ---------------------------------------------------------------------------
// Partial logit stats per (b, 1/8 of VOCAB)
// ---------------------------------------------------------------------------
#define VCHUNK 6284
__global__ __launch_bounds__(256) void stats_part_k(
    const float* __restrict__ logits, float* __restrict__ vmax,
    float* __restrict__ vsum, int ldc)
{
    int b = blockIdx.y, ch = blockIdx.x;
    int v0 = ch * VCHUNK;
    int v1 = min(v0 + VCHUNK, VOCAB);
    const float* row = logits + (size_t)b * ldc;
    float m = -INFINITY;
    for (int v = v0 + threadIdx.x; v < v1; v += 256) m = fmaxf(m, row[v]);
    __shared__ float red[4];
    for (int off = 32; off; off >>= 1) m = fmaxf(m, __shfl_xor(m, off));
    int wave = threadIdx.x >> 6, lane = threadIdx.x & 63;
    if (lane == 0) red[wave] = m;
    __syncthreads();
    m = fmaxf(fmaxf(red[0], red[1]), fmaxf(red[2], red[3]));
    float ssum = 0.0f;
    for (int v = v0 + threadIdx.x; v < v1; v += 256) ssum += expf(row[v] - m);
    for (int off = 32; off; off >>= 1) ssum += __shfl_xor(ssum, off);
    __syncthreads();
    if (lane == 0) red[wave] = ssum;
    __syncthreads();
    if (threadIdx.x == 0) {
        vmax[b * 8 + ch] = m;
        vsum[b * 8 + ch] = red[0] + red[1] + red[2] + red[3];
    }
}

// ---------------------------------------------------------------------------
// Softmax normalize over VOCAB
// ---------------------------------------------------------------------------
__global__ __launch_bounds__(256) void softmax_v_k(
    const float* __restrict__ logits, const float* __restrict__ vmax,
    const float* __restrict__ vsum, float* __restrict__ out, int ldc)
{
    int b = blockIdx.y;
    float m = -INFINITY;
#pragma unroll
    for (int i = 0; i < 8; ++i) m = fmaxf(m, vmax[b * 8 + i]);
    float tot = 0.0f;
#pragma unroll
    for (int i = 0; i < 8; ++i) tot += vsum[b * 8 + i] * expf(vmax[b * 8 + i] - m);
    float inv = 1.0f / tot;
    int v = blockIdx.x * 1024 + threadIdx.x * 4;
    if (v + 3 < VOCAB) {
        float4 lv = *reinterpret_cast<const float4*>(logits + (size_t)b * ldc + v);
        float4 o;
        o.x = expf(lv.x - m) * inv; o.y = expf(lv.y - m) * inv;
        o.z = expf(lv.z - m) * inv; o.w = expf(lv.w - m) * inv;
        *reinterpret_cast<float4*>(out + (size_t)b * VOCAB + v) = o;
    } else {
        for (int k = 0; k < 4 && v + k < VOCAB; ++k)
            out[(size_t)b * VOCAB + v + k] = expf(logits[(size_t)b * ldc + v + k] - m) * inv;
    }
}

// ---------------------------------------------------------------------------
extern "C" void kernel_launch(void* const* d_in, const int* in_sizes, int n_in,
                              void* d_out, int out_size, void* d_ws, size_t ws_size,
                              hipStream_t stream)
{
    const int*   input_step  = (const int*)  d_in[0];
    const float* last_hidden = (const float*)d_in[1];
    const float* enc         = (const float*)d_in[2];
    const float* emb         = (const float*)d_in[3];
    const float* w_ih0       = (const float*)d_in[4];
    const float* w_hh0       = (const float*)d_in[5];
    const float* b_ih0       = (const float*)d_in[6];
    const float* b_hh0       = (const float*)d_in[7];
    const float* w_ih1       = (const float*)d_in[8];
    const float* w_hh1       = (const float*)d_in[9];
    const float* b_ih1       = (const float*)d_in[10];
    const float* b_hh1       = (const float*)d_in[11];
    const float* concat_w    = (const float*)d_in[12];
    const float* concat_b    = (const float*)d_in[13];
    const float* out_w       = (const float*)d_in[14];
    const float* out_b       = (const float*)d_in[15];

    float* out = (float*)d_out;
    float* out_probs  = out;
    float* out_hidden = out + (size_t)BATCH * VOCAB;

    float* ws   = (float*)d_ws;
    float* big  = ws;
    float* pgi0 = big;
    float* pgh0 = big + 786432;
    float* pgh1 = big + 1572864;
    float* pgi1 = big;              // alias
    float* pctx = big;              // alias
    float* pco  = big;              // alias
    float* logits = ws + 2359296;                   // 64*LOGITS_LD
    float* ci   = logits + (size_t)64 * LOGITS_LD;  // 131072
    float* h0   = ci + 131072;                      // 65536
    float* pm   = h0 + 65536;                       // 2048
    float* ps   = pm + 2048;                        // 2048
    float* vmax = ps + 2048;                        // 512
    float* vsum = vmax + 512;                       // 512
    ushort* co_bf = (ushort*)(vsum + 512);          // 65536 ushorts

    Prob P0 = { emb,         input_step, w_ih0, nullptr, pgi0, 3 * HID, EMB, 3 * HID };
    Prob P1 = { last_hidden, nullptr,    w_hh0, nullptr, pgh0, 3 * HID, HID, 3 * HID };
    Prob P2 = { last_hidden + 64 * HID, nullptr, w_hh1, nullptr, pgh1, 3 * HID, HID, 3 * HID };

    // 1. triple GEMM: gi0 (emb-gather), gh0, gh1 — independent. split-K 4.
    gemm_k<256, 0, 0><<<dim3(96, 3, 4), 128, 0, stream>>>(P0, P1, P2);

    // 2. gate layer 0 -> h0 (fp32), out_hidden[0]
    gru_gate_k<4, 4><<<256, 256, 0, stream>>>(pgi0, pgh0, b_ih0, b_hh0, last_hidden,
                                              out_hidden, h0, nullptr);

    // 3. gi1 = h0 @ w_ih1, split-K 8
    Prob PB = { h0, nullptr, w_ih1, nullptr, pgi1, 3 * HID, HID, 3 * HID };
    gemm_k<128, 0, 0><<<dim3(96, 1, 8), 128, 0, stream>>>(PB, PB, PB);

    // 4. gate layer 1 -> out_hidden[1], ci[:, :1024]
    gru_gate_k<8, 4><<<256, 256, 0, stream>>>(pgi1, pgh1, b_ih1, b_hh1,
                                              last_hidden + 64 * HID,
                                              out_hidden + 64 * HID, nullptr, ci);

    // 5. attention: single-pass flash over 32 chunks of 16, then combine
    attn_fused_k<<<dim3(NCHUNK, BATCH), 256, 0, stream>>>(
        out_hidden + 64 * HID, enc, pctx, pm, ps);
    attn_comb_k<<<BATCH, 256, 0, stream>>>(pctx, pm, ps, ci);

    // 6. concat projection: split-K 8 + tanh combine -> co_bf (bf16)
    Prob PC = { ci, nullptr, concat_w, nullptr, pco, HID, 2 * HID, HID };
    gemm_k<256, 0, 0><<<dim3(32, 1, 8), 128, 0, stream>>>(PC, PC, PC);
    concat_comb_k<<<256, 256, 0, stream>>>(pco, concat_b, co_bf);

    // 7. logits GEMM: 2-phase global_load_lds pipeline, 64 vocab rows/block
    logits_k<<<(VOCAB + 63) / 64, 256, 0, stream>>>(co_bf, out_w, out_b, logits);

    // 8. vocab softmax
    stats_part_k<<<dim3(8, BATCH), 256, 0, stream>>>(logits, vmax, vsum, LOGITS_LD);
    softmax_v_k<<<dim3((VOCAB + 1023) / 1024, BATCH), 256, 0, stream>>>(
        logits, vmax, vsum, out_probs, LOGITS_LD);
}

// Round 8
// 194.437 us; speedup vs baseline: 1.2588x; 1.0127x over previous
//
#include <hip/hip_runtime.h>
#include <hip/hip_bf16.h>
#include <math.h>

#define VOCAB 50257
#define EMB   1024
#define HID   1024
#define BATCH 64
#define SEQ   512
#define LOGITS_LD 50304
#define SCH   16                  // s-rows per attention chunk
#define NCHUNK (SEQ / SCH)        // 32
#define NSLAB 786                 // 64-vocab-row slabs

typedef __attribute__((ext_vector_type(8))) short bf16x8;
typedef __attribute__((ext_vector_type(4))) float f32x4;

typedef const __attribute__((address_space(1))) unsigned int gu32_t;
typedef __attribute__((address_space(3))) unsigned int lu32_t;

__device__ inline short f2bf(float x) {
    __hip_bfloat16 h = __float2bfloat16(x);
    return *reinterpret_cast<short*>(&h);
}

__device__ inline bf16x8 cvt8(const float4& a, const float4& b) {
    bf16x8 r;
    r[0] = f2bf(a.x); r[1] = f2bf(a.y); r[2] = f2bf(a.z); r[3] = f2bf(a.w);
    r[4] = f2bf(b.x); r[5] = f2bf(b.y); r[6] = f2bf(b.z); r[7] = f2bf(b.w);
    return r;
}

// ---------------------------------------------------------------------------
// Direct-stream MFMA GEMM for the small GEMMs (unchanged from round 6/7).
// ---------------------------------------------------------------------------
struct Prob {
    const void*  A;
    const int*   gidx;
    const float* W;
    const float* bias;
    float*       C;
    int N, K, ldc;
};

template <int KSLEN, int ADD_BIAS, int A_BF16>
__global__ __launch_bounds__(128, 2) void gemm_k(Prob p0, Prob p1, Prob p2)
{
    Prob P = (blockIdx.y == 0) ? p0 : ((blockIdx.y == 1) ? p1 : p2);

    const int lane = threadIdx.x & 63;
    const int wv   = threadIdx.x >> 6;
    const int rowi = lane & 15;
    const int kgi  = lane >> 4;
    const int col  = blockIdx.x * 32 + wv * 16 + rowi;
    const int wcol = min(col, P.N - 1);
    const int kbase = blockIdx.z * KSLEN + kgi * 8;

    const float* wp = P.W + (size_t)wcol * P.K + kbase;

    const float*  af[4];
    const ushort* ah[4];
#pragma unroll
    for (int mt = 0; mt < 4; ++mt) {
        int r  = rowi + mt * 16;
        int ar = P.gidx ? P.gidx[r] : r;
        af[mt] = (const float*) P.A + (size_t)ar * P.K + kbase;
        ah[mt] = (const ushort*)P.A + (size_t)ar * P.K + kbase;
    }

    f32x4 acc[4] = {};

    float4 wa0, wb0, wa1, wb1;
    bf16x8 h0b[4], h1b[4];
    float4 f0a[4], f0b[4], f1a[4], f1b[4];

    wa0 = *(const float4*)(wp);
    wb0 = *(const float4*)(wp + 4);
#pragma unroll
    for (int mt = 0; mt < 4; ++mt) {
        if (A_BF16) h0b[mt] = *(const bf16x8*)(ah[mt]);
        else { f0a[mt] = *(const float4*)(af[mt]); f0b[mt] = *(const float4*)(af[mt] + 4); }
    }
    wa1 = *(const float4*)(wp + 32);
    wb1 = *(const float4*)(wp + 36);
#pragma unroll
    for (int mt = 0; mt < 4; ++mt) {
        if (A_BF16) h1b[mt] = *(const bf16x8*)(ah[mt] + 32);
        else { f1a[mt] = *(const float4*)(af[mt] + 32); f1b[mt] = *(const float4*)(af[mt] + 36); }
    }

#pragma unroll
    for (int ks = 0; ks < KSLEN; ks += 64) {
        {
            float4 nwa = {}, nwb = {};
            bf16x8 nh[4] = {};
            float4 nfa[4] = {}, nfb[4] = {};
            if (ks + 64 < KSLEN) {
                nwa = *(const float4*)(wp + ks + 64);
                nwb = *(const float4*)(wp + ks + 68);
#pragma unroll
                for (int mt = 0; mt < 4; ++mt) {
                    if (A_BF16) nh[mt] = *(const bf16x8*)(ah[mt] + ks + 64);
                    else { nfa[mt] = *(const float4*)(af[mt] + ks + 64);
                           nfb[mt] = *(const float4*)(af[mt] + ks + 68); }
                }
            }
            bf16x8 b = cvt8(wa0, wb0);
#pragma unroll
            for (int mt = 0; mt < 4; ++mt) {
                bf16x8 a;
                if (A_BF16) a = h0b[mt]; else a = cvt8(f0a[mt], f0b[mt]);
                acc[mt] = __builtin_amdgcn_mfma_f32_16x16x32_bf16(a, b, acc[mt], 0, 0, 0);
            }
            wa0 = nwa; wb0 = nwb;
#pragma unroll
            for (int mt = 0; mt < 4; ++mt) {
                if (A_BF16) h0b[mt] = nh[mt];
                else { f0a[mt] = nfa[mt]; f0b[mt] = nfb[mt]; }
            }
        }
        {
            float4 nwa = {}, nwb = {};
            bf16x8 nh[4] = {};
            float4 nfa[4] = {}, nfb[4] = {};
            if (ks + 96 < KSLEN) {
                nwa = *(const float4*)(wp + ks + 96);
                nwb = *(const float4*)(wp + ks + 100);
#pragma unroll
                for (int mt = 0; mt < 4; ++mt) {
                    if (A_BF16) nh[mt] = *(const bf16x8*)(ah[mt] + ks + 96);
                    else { nfa[mt] = *(const float4*)(af[mt] + ks + 96);
                           nfb[mt] = *(const float4*)(af[mt] + ks + 100); }
                }
            }
            bf16x8 b = cvt8(wa1, wb1);
#pragma unroll
            for (int mt = 0; mt < 4; ++mt) {
                bf16x8 a;
                if (A_BF16) a = h1b[mt]; else a = cvt8(f1a[mt], f1b[mt]);
                acc[mt] = __builtin_amdgcn_mfma_f32_16x16x32_bf16(a, b, acc[mt], 0, 0, 0);
            }
            wa1 = nwa; wb1 = nwb;
#pragma unroll
            for (int mt = 0; mt < 4; ++mt) {
                if (A_BF16) h1b[mt] = nh[mt];
                else { f1a[mt] = nfa[mt]; f1b[mt] = nfb[mt]; }
            }
        }
    }

    if (col < P.N) {
        float bv = ADD_BIAS ? P.bias[col] : 0.0f;
        float* C = P.C + (size_t)blockIdx.z * 64 * P.ldc;
#pragma unroll
        for (int mt = 0; mt < 4; ++mt)
#pragma unroll
            for (int r = 0; r < 4; ++r) {
                int row = mt * 16 + kgi * 4 + r;
                C[(size_t)row * P.ldc + col] = acc[mt][r] + bv;
            }
    }
}

// ---------------------------------------------------------------------------
// Persistent logits GEMM + fused per-slab softmax stats.
// Grid = 256 blocks (1/CU by LDS: co 128 KB). Each block:
//   - stages co (64x1024 bf16) in LDS ONCE, XOR-swizzled via source (rule 21)
//   - work-queue loop over 786 slabs of 64 vocab rows:
//       W streamed to registers (depth-2, no barriers in K-loop), 32 K-steps
//       epilogue: write logits + per-slab (max, sumexp) partials per batch row
// ---------------------------------------------------------------------------
__global__ __launch_bounds__(256) void logits_pers_k(
    const ushort* __restrict__ co_bf, const float* __restrict__ W,
    const float* __restrict__ bias, float* __restrict__ logits,
    float* __restrict__ pmax, float* __restrict__ psum, int* __restrict__ ctr)
{
    __shared__ ushort co_s[64 * 1024];        // 128 KB
    __shared__ float smax[4][64], ssum[4][64];
    __shared__ int slab_s;

    const int tid  = threadIdx.x;
    const int lane = tid & 63;
    const int wv   = tid >> 6;
    const int rowi = lane & 15;
    const int kgi  = lane >> 4;

    // ---- stage co once: 32 rounds x 4 KB, pre-swizzled source ----
#pragma unroll
    for (int rnd = 0; rnd < 32; ++rnd) {
        int o     = rnd * 4096 + tid * 16;     // linear LDS byte offset
        int row   = o >> 11;                   // 2048 B per batch row
        int inner = o & 2047;
        int src   = (row << 11) + (inner ^ ((row & 7) << 4));
        __builtin_amdgcn_global_load_lds(
            (gu32_t*)((const char*)co_bf + src),
            (lu32_t*)(((char*)co_s) + rnd * 4096 + wv * 1024), 16, 0, 0);
    }
    __syncthreads();

    const int rloc = wv * 16 + rowi;           // vocab row within slab

    while (true) {
        if (tid == 0) slab_s = atomicAdd(ctr, 1);
        __syncthreads();
        const int slab = slab_s;
        if (slab >= NSLAB) break;

        const int nblk = slab * 64;
        const int wrow = min(nblk + rloc, VOCAB - 1);
        const float* wp = W + (size_t)wrow * 1024 + kgi * 8;

        f32x4 acc[4] = {};
        float4 wa0 = *(const float4*)(wp);
        float4 wb0 = *(const float4*)(wp + 4);
        float4 wa1 = *(const float4*)(wp + 32);
        float4 wb1 = *(const float4*)(wp + 36);

#pragma unroll
        for (int s = 0; s < 32; s += 2) {
            float4 na0 = {}, nb0 = {}, na1 = {}, nb1 = {};
            if (s + 2 < 32) {
                na0 = *(const float4*)(wp + (s + 2) * 32);
                nb0 = *(const float4*)(wp + (s + 2) * 32 + 4);
            }
            if (s + 3 < 32) {
                na1 = *(const float4*)(wp + (s + 3) * 32);
                nb1 = *(const float4*)(wp + (s + 3) * 32 + 4);
            }
            // even step s
            {
                bf16x8 wf = cvt8(wa0, wb0);
                const int kb = s * 64 + kgi * 16;
#pragma unroll
                for (int cf = 0; cf < 4; ++cf) {
                    int row = cf * 16 + rowi;
                    const char* p = ((const char*)co_s) + row * 2048 +
                                    (kb ^ ((row & 7) << 4));
                    bf16x8 a = *(const bf16x8*)p;
                    acc[cf] = __builtin_amdgcn_mfma_f32_16x16x32_bf16(wf, a, acc[cf], 0, 0, 0);
                }
            }
            // odd step s+1
            {
                bf16x8 wf = cvt8(wa1, wb1);
                const int kb = (s + 1) * 64 + kgi * 16;
#pragma unroll
                for (int cf = 0; cf < 4; ++cf) {
                    int row = cf * 16 + rowi;
                    const char* p = ((const char*)co_s) + row * 2048 +
                                    (kb ^ ((row & 7) << 4));
                    bf16x8 a = *(const bf16x8*)p;
                    acc[cf] = __builtin_amdgcn_mfma_f32_16x16x32_bf16(wf, a, acc[cf], 0, 0, 0);
                }
            }
            wa0 = na0; wb0 = nb0; wa1 = na1; wb1 = nb1;
        }

        // ---- epilogue: bias, store logits, per-slab stats ----
        const int nb = nblk + wv * 16 + kgi * 4;    // vocab base (always < 50304)
        float vals[4][4];
#pragma unroll
        for (int cf = 0; cf < 4; ++cf) {
            int b = cf * 16 + rowi;
#pragma unroll
            for (int r = 0; r < 4; ++r)
                vals[cf][r] = acc[cf][r] + bias[min(nb + r, VOCAB - 1)];
            float4 o = {vals[cf][0], vals[cf][1], vals[cf][2], vals[cf][3]};
            *(float4*)(logits + (size_t)b * LOGITS_LD + nb) = o;   // LD padded, safe
        }
        // wave-level stats: reduce over kgi (lanes ^16, ^32)
#pragma unroll
        for (int cf = 0; cf < 4; ++cf) {
            float m = -INFINITY;
#pragma unroll
            for (int r = 0; r < 4; ++r)
                if (nb + r < VOCAB) m = fmaxf(m, vals[cf][r]);
            m = fmaxf(m, __shfl_xor(m, 16));
            m = fmaxf(m, __shfl_xor(m, 32));
            float sm = 0.0f;
#pragma unroll
            for (int r = 0; r < 4; ++r)
                if (nb + r < VOCAB) sm += expf(vals[cf][r] - m);
            sm += __shfl_xor(sm, 16);
            sm += __shfl_xor(sm, 32);
            if (kgi == 0) { smax[wv][cf * 16 + rowi] = m; ssum[wv][cf * 16 + rowi] = sm; }
        }
        __syncthreads();
        if (tid < 64) {
            float m = fmaxf(fmaxf(smax[0][tid], smax[1][tid]),
                            fmaxf(smax[2][tid], smax[3][tid]));
            float t = 0.0f;
#pragma unroll
            for (int w = 0; w < 4; ++w) {
                float sw = ssum[w][tid];
                t += (sw > 0.0f) ? sw * expf(smax[w][tid] - m) : 0.0f;
            }
            pmax[(size_t)slab * 64 + tid] = m;
            psum[(size_t)slab * 64 + tid] = t;
        }
        __syncthreads();   // protect smax/ssum and slab_s for next iteration
    }
}

// ---------------------------------------------------------------------------
// Combine per-slab stats -> per-batch global max and 1/sum
// ---------------------------------------------------------------------------
__global__ __launch_bounds__(256) void vfinal_k(
    const float* __restrict__ pmax, const float* __restrict__ psum,
    float* __restrict__ gm, float* __restrict__ ginv)
{
    const int b = blockIdx.x;
    __shared__ float red[4];
    float m = -INFINITY;
    for (int s = threadIdx.x; s < NSLAB; s += 256)
        m = fmaxf(m, pmax[(size_t)s * 64 + b]);
    for (int off = 32; off; off >>= 1) m = fmaxf(m, __shfl_xor(m, off));
    int wv = threadIdx.x >> 6, lane = threadIdx.x & 63;
    if (lane == 0) red[wv] = m;
    __syncthreads();
    m = fmaxf(fmaxf(red[0], red[1]), fmaxf(red[2], red[3]));
    float t = 0.0f;
    for (int s = threadIdx.x; s < NSLAB; s += 256)
        t += psum[(size_t)s * 64 + b] * expf(pmax[(size_t)s * 64 + b] - m);
    for (int off = 32; off; off >>= 1) t += __shfl_xor(t, off);
    __syncthreads();
    if (lane == 0) red[wv] = t;
    __syncthreads();
    if (threadIdx.x == 0) { gm[b] = m; ginv[b] = 1.0f / (red[0] + red[1] + red[2] + red[3]); }
}

// ---------------------------------------------------------------------------
// GRU gate fusion over split-K partials (NZI for gi, NZH for gh).
// ---------------------------------------------------------------------------
template <int NZI, int NZH>
__global__ __launch_bounds__(256) void gru_gate_k(
    const float* __restrict__ pgi, const float* __restrict__ pgh,
    const float* __restrict__ b_ih, const float* __restrict__ b_hh,
    const float* __restrict__ hprev, float* __restrict__ out_hidden,
    float* __restrict__ h_out, float* __restrict__ ci)
{
    int i = blockIdx.x * 256 + threadIdx.x;
    int b = i >> 10, j = i & 1023;
    size_t base = (size_t)b * 3072 + j;
    float ir = b_ih[j], iz = b_ih[j + 1024], in_ = b_ih[j + 2048];
    float hr = b_hh[j], hz = b_hh[j + 1024], hn  = b_hh[j + 2048];
#pragma unroll
    for (int z = 0; z < NZI; ++z) {
        size_t o = (size_t)z * 64 * 3072 + base;
        ir += pgi[o]; iz += pgi[o + 1024]; in_ += pgi[o + 2048];
    }
#pragma unroll
    for (int z = 0; z < NZH; ++z) {
        size_t o = (size_t)z * 64 * 3072 + base;
        hr += pgh[o]; hz += pgh[o + 1024]; hn  += pgh[o + 2048];
    }
    float r = 1.0f / (1.0f + expf(-(ir + hr)));
    float z = 1.0f / (1.0f + expf(-(iz + hz)));
    float n = tanhf(in_ + r * hn);
    float v = (1.0f - z) * n + z * hprev[i];
    out_hidden[i] = v;
    if (h_out) h_out[i] = v;
    if (ci)    ci[(size_t)b * 2048 + j] = v;
}

// ---------------------------------------------------------------------------
// Single-pass flash attention chunk: per (chunk of 16 s, b).
// ---------------------------------------------------------------------------
__global__ __launch_bounds__(256) void attn_fused_k(
    const float* __restrict__ h1, const float* __restrict__ enc,
    float* __restrict__ pctx, float* __restrict__ pm, float* __restrict__ ps)
{
    const int b = blockIdx.y, ck = blockIdx.x;
    __shared__ float hs[HID];
    __shared__ float es[SCH][HID];
    __shared__ float sc[SCH];
    const int tid = threadIdx.x, wv = tid >> 6, lane = tid & 63;

    ((float4*)hs)[tid] = ((const float4*)(h1 + (size_t)b * HID))[tid];
    const float* ebase = enc + ((size_t)(ck * SCH) * BATCH + b) * HID;
#pragma unroll
    for (int i = 0; i < SCH; ++i) {
        int idx = tid + i * 256;
        int r = idx >> 8, c = idx & 255;
        ((float4*)es[r])[c] = ((const float4*)(ebase + (size_t)r * BATCH * HID))[c];
    }
    __syncthreads();

#pragma unroll
    for (int i = 0; i < 4; ++i) {
        int r = wv * 4 + i;
        float acc = 0.0f;
#pragma unroll
        for (int seg = 0; seg < 4; ++seg) {
            float4 ev = ((const float4*)es[r])[lane + seg * 64];
            float4 hv = ((const float4*)hs)[lane + seg * 64];
            acc += ev.x * hv.x + ev.y * hv.y + ev.z * hv.z + ev.w * hv.w;
        }
        for (int off = 32; off; off >>= 1) acc += __shfl_down(acc, off);
        if (lane == 0) sc[r] = acc;
    }
    __syncthreads();

    float m = sc[0];
#pragma unroll
    for (int s = 1; s < SCH; ++s) m = fmaxf(m, sc[s]);
    float p[SCH];
    float sum = 0.0f;
#pragma unroll
    for (int s = 0; s < SCH; ++s) { p[s] = expf(sc[s] - m); sum += p[s]; }

    float4 cacc = {0.0f, 0.0f, 0.0f, 0.0f};
#pragma unroll
    for (int s = 0; s < SCH; ++s) {
        float4 ev = ((const float4*)es[s])[tid];
        cacc.x += p[s] * ev.x; cacc.y += p[s] * ev.y;
        cacc.z += p[s] * ev.z; cacc.w += p[s] * ev.w;
    }
    ((float4*)(pctx + ((size_t)ck * BATCH + b) * HID))[tid] = cacc;
    if (tid == 0) { pm[b * NCHUNK + ck] = m; ps[b * NCHUNK + ck] = sum; }
}

// ---------------------------------------------------------------------------
// Attention combine: merge 32 chunk partials -> ci[:,1024:] (fp32)
// ---------------------------------------------------------------------------
__global__ __launch_bounds__(256) void attn_comb_k(
    const float* __restrict__ pctx, const float* __restrict__ pm,
    const float* __restrict__ ps, float* __restrict__ ci)
{
    const int b = blockIdx.x, tid = threadIdx.x;
    float m = -INFINITY;
#pragma unroll
    for (int c = 0; c < NCHUNK; ++c) m = fmaxf(m, pm[b * NCHUNK + c]);
    float w[NCHUNK]; float tot = 0.0f;
#pragma unroll
    for (int c = 0; c < NCHUNK; ++c) {
        w[c] = expf(pm[b * NCHUNK + c] - m);
        tot += ps[b * NCHUNK + c] * w[c];
    }
    float inv = 1.0f / tot;
    float4 acc = {0.0f, 0.0f, 0.0f, 0.0f};
#pragma unroll
    for (int c = 0; c < NCHUNK; ++c) {
        float4 v = ((const float4*)(pctx + ((size_t)c * BATCH + b) * HID))[tid];
        acc.x += w[c] * v.x; acc.y += w[c] * v.y;
        acc.z += w[c] * v.z; acc.w += w[c] * v.w;
    }
    float4 o = {acc.x * inv, acc.y * inv, acc.z * inv, acc.w * inv};
    ((float4*)(ci + (size_t)b * 2048 + 1024))[tid] = o;
}

// ---------------------------------------------------------------------------
// Concat combine: co_bf = bf16(tanh(sum of 8 partials + bias)); init counter.
// ---------------------------------------------------------------------------
__global__ __launch_bounds__(256) void concat_comb_k(
    const float* __restrict__ pco, const float* __restrict__ bias,
    ushort* __restrict__ co_bf, int* __restrict__ ctr)
{
    if (blockIdx.x == 0 && threadIdx.x == 0) *ctr = 0;
    int i = blockIdx.x * 256 + threadIdx.x;
    int j = i & 1023;
    float v = bias[j];
#pragma unroll
    for (int z = 0; z < 8; ++z) v += pco[(size_t)z * 65536 + i];
    co_bf[i] = (ushort)f2bf(tanhf(v));
}

// ---------------------------------------------------------------------------
// Softmax normalize over VOCAB using precomputed gm/ginv
// ---------------------------------------------------------------------------
__global__ __launch_bounds__(256) void softmax_v_k(
    const float* __restrict__ logits, const float* __restrict__ gm,
    const float* __restrict__ ginv, float* __restrict__ out)
{
    int b = blockIdx.y;
    float m = gm[b], inv = ginv[b];
    int v = blockIdx.x * 1024 + threadIdx.x * 4;
    if (v + 3 < VOCAB) {
        float4 lv = *reinterpret_cast<const float4*>(logits + (size_t)b * LOGITS_LD + v);
        float4 o;
        o.x = expf(lv.x - m) * inv; o.y = expf(lv.y - m) * inv;
        o.z = expf(lv.z - m) * inv; o.w = expf(lv.w - m) * inv;
        *reinterpret_cast<float4*>(out + (size_t)b * VOCAB + v) = o;
    } else {
        for (int k = 0; k < 4 && v + k < VOCAB; ++k)
            out[(size_t)b * VOCAB + v + k] = expf(logits[(size_t)b * LOGITS_LD + v + k] - m) * inv;
    }
}

// ---------------------------------------------------------------------------
extern "C" void kernel_launch(void* const* d_in, const int* in_sizes, int n_in,
                              void* d_out, int out_size, void* d_ws, size_t ws_size,
                              hipStream_t stream)
{
    const int*   input_step  = (const int*)  d_in[0];
    const float* last_hidden = (const float*)d_in[1];
    const float* enc         = (const float*)d_in[2];
    const float* emb         = (const float*)d_in[3];
    const float* w_ih0       = (const float*)d_in[4];
    const float* w_hh0       = (const float*)d_in[5];
    const float* b_ih0       = (const float*)d_in[6];
    const float* b_hh0       = (const float*)d_in[7];
    const float* w_ih1       = (const float*)d_in[8];
    const float* w_hh1       = (const float*)d_in[9];
    const float* b_ih1       = (const float*)d_in[10];
    const float* b_hh1       = (const float*)d_in[11];
    const float* concat_w    = (const float*)d_in[12];
    const float* concat_b    = (const float*)d_in[13];
    const float* out_w       = (const float*)d_in[14];
    const float* out_b       = (const float*)d_in[15];

    float* out = (float*)d_out;
    float* out_probs  = out;
    float* out_hidden = out + (size_t)BATCH * VOCAB;

    float* ws   = (float*)d_ws;
    float* big  = ws;                               // aliased region
    float* pgi0 = big;
    float* pgh0 = big + 786432;
    float* pgh1 = big + 1572864;
    float* pgi1 = big;                              // alias
    float* pctx = big;                              // alias
    float* pco  = big;                              // alias
    float* logits = ws + 2359296;                   // 64*LOGITS_LD = 3219456
    float* ci   = logits + (size_t)64 * LOGITS_LD;  // 131072
    float* h0   = ci + 131072;                      // 65536
    float* pm   = h0 + 65536;                       // 2048
    float* ps   = pm + 2048;                        // 2048
    float* pmax = ps + 2048;                        // NSLAB*64 = 50304
    float* psum = pmax + 50304;                     // 50304
    float* gm   = psum + 50304;                     // 64
    float* ginv = gm + 64;                          // 64
    int*   ctr  = (int*)(ginv + 64);                // 16 floats reserved
    ushort* co_bf = (ushort*)(ginv + 64 + 16);      // 65536 ushorts

    Prob P0 = { emb,         input_step, w_ih0, nullptr, pgi0, 3 * HID, EMB, 3 * HID };
    Prob P1 = { last_hidden, nullptr,    w_hh0, nullptr, pgh0, 3 * HID, HID, 3 * HID };
    Prob P2 = { last_hidden + 64 * HID, nullptr, w_hh1, nullptr, pgh1, 3 * HID, HID, 3 * HID };

    // 1. triple GEMM: gi0 (emb-gather), gh0, gh1 — independent. split-K 4.
    gemm_k<256, 0, 0><<<dim3(96, 3, 4), 128, 0, stream>>>(P0, P1, P2);

    // 2. gate layer 0 -> h0 (fp32), out_hidden[0]
    gru_gate_k<4, 4><<<256, 256, 0, stream>>>(pgi0, pgh0, b_ih0, b_hh0, last_hidden,
                                              out_hidden, h0, nullptr);

    // 3. gi1 = h0 @ w_ih1, split-K 8
    Prob PB = { h0, nullptr, w_ih1, nullptr, pgi1, 3 * HID, HID, 3 * HID };
    gemm_k<128, 0, 0><<<dim3(96, 1, 8), 128, 0, stream>>>(PB, PB, PB);

    // 4. gate layer 1 -> out_hidden[1], ci[:, :1024]
    gru_gate_k<8, 4><<<256, 256, 0, stream>>>(pgi1, pgh1, b_ih1, b_hh1,
                                              last_hidden + 64 * HID,
                                              out_hidden + 64 * HID, nullptr, ci);

    // 5. attention: single-pass flash over 32 chunks of 16, then combine
    attn_fused_k<<<dim3(NCHUNK, BATCH), 256, 0, stream>>>(
        out_hidden + 64 * HID, enc, pctx, pm, ps);
    attn_comb_k<<<BATCH, 256, 0, stream>>>(pctx, pm, ps, ci);

    // 6. concat projection: split-K 8 + tanh combine -> co_bf (bf16) + ctr init
    Prob PC = { ci, nullptr, concat_w, nullptr, pco, HID, 2 * HID, HID };
    gemm_k<256, 0, 0><<<dim3(32, 1, 8), 128, 0, stream>>>(PC, PC, PC);
    concat_comb_k<<<256, 256, 0, stream>>>(pco, concat_b, co_bf, ctr);

    // 7. persistent logits GEMM + fused per-slab stats
    logits_pers_k<<<256, 256, 0, stream>>>(co_bf, out_w, out_b, logits, pmax, psum, ctr);

    // 8. stats combine + softmax normalize
    vfinal_k<<<BATCH, 256, 0, stream>>>(pmax, psum, gm, ginv);
    softmax_v_k<<<dim3((VOCAB + 1023) / 1024, BATCH), 256, 0, stream>>>(
        logits, gm, ginv, out_probs);
}